// Round 6
// baseline (633.003 us; speedup 1.0000x reference)
//
#include <hip/hip_runtime.h>
#include <cmath>

namespace {

constexpr int B_ = 2, T_ = 2048, C_ = 1024, H_ = 16;
constexpr float GAMMA_INV = 0.125f;   // 1/GAMMA
constexpr float SCALE = 0.125f;       // 1/sqrt(D), D=64

typedef __attribute__((ext_vector_type(8))) short bf16x8;
typedef __attribute__((ext_vector_type(4))) float f32x4;
typedef unsigned short ushort_t;

__device__ __forceinline__ ushort_t f2bf(float x) {
  union { float f; unsigned int u; } v; v.f = x;
  unsigned int r = (v.u + 0x7fffu + ((v.u >> 16) & 1u)) >> 16;
  return (ushort_t)r;
}

__device__ __forceinline__ f32x4 mfma16(bf16x8 a, bf16x8 b, f32x4 c) {
  return __builtin_amdgcn_mfma_f32_16x16x32_bf16(a, b, c, 0, 0, 0);
}

// ---------------- bf16 MFMA GEMM, register-staged LDS ----------------
// C(M,N) fp32 = A(M,K) bf16 row-major @ Bt(N,K)^T bf16 row-major
constexpr int GBM = 128, GBN = 128, GBK = 32;
constexpr int LDP = 40;   // padded row: 40 ushorts = 80 B (16B-aligned, 2-way banks)

__global__ __launch_bounds__(256) void gemm_bt(const ushort_t* __restrict__ A,
                                               const ushort_t* __restrict__ Bt,
                                               float* __restrict__ Cm,
                                               int N, int K) {
  __shared__ alignas(16) ushort_t As[GBM][LDP];
  __shared__ alignas(16) ushort_t Bs[GBN][LDP];
  const int tid = threadIdx.x;
  const int m0 = blockIdx.y * GBM, n0 = blockIdx.x * GBN;
  const int wv = tid >> 6;
  const int ln = tid & 63;
  const int lr = ln & 15, hi = ln >> 4;
  const int wr = wv >> 1, wc = wv & 1;

  const int sr0 = tid >> 2, sc0 = (tid & 3) * 8;
  const int sr1 = sr0 + 64;
  const ushort_t* gA0 = A + (size_t)(m0 + sr0) * K + sc0;
  const ushort_t* gA1 = A + (size_t)(m0 + sr1) * K + sc0;
  const ushort_t* gB0 = Bt + (size_t)(n0 + sr0) * K + sc0;
  const ushort_t* gB1 = Bt + (size_t)(n0 + sr1) * K + sc0;

  f32x4 acc[4][4];
  #pragma unroll
  for (int m = 0; m < 4; ++m)
    #pragma unroll
    for (int n = 0; n < 4; ++n)
      #pragma unroll
      for (int r = 0; r < 4; ++r) acc[m][n][r] = 0.0f;

  for (int k0 = 0; k0 < K; k0 += GBK) {
    uint4 a0 = *(const uint4*)(gA0 + k0);
    uint4 a1 = *(const uint4*)(gA1 + k0);
    uint4 b0 = *(const uint4*)(gB0 + k0);
    uint4 b1 = *(const uint4*)(gB1 + k0);
    *(uint4*)&As[sr0][sc0] = a0;
    *(uint4*)&As[sr1][sc0] = a1;
    *(uint4*)&Bs[sr0][sc0] = b0;
    *(uint4*)&Bs[sr1][sc0] = b1;
    __syncthreads();
    bf16x8 af[4], bfr[4];
    #pragma unroll
    for (int m = 0; m < 4; ++m)
      af[m] = *(const bf16x8*)&As[wr * 64 + m * 16 + lr][hi * 8];
    #pragma unroll
    for (int n = 0; n < 4; ++n)
      bfr[n] = *(const bf16x8*)&Bs[wc * 64 + n * 16 + lr][hi * 8];
    #pragma unroll
    for (int m = 0; m < 4; ++m)
      #pragma unroll
      for (int n = 0; n < 4; ++n)
        acc[m][n] = mfma16(af[m], bfr[n], acc[m][n]);
    __syncthreads();
  }
  #pragma unroll
  for (int m = 0; m < 4; ++m) {
    #pragma unroll
    for (int r = 0; r < 4; ++r) {
      const int row = m0 + wr * 64 + m * 16 + hi * 4 + r;
      float* Crow = Cm + (size_t)row * N + n0 + wc * 64;
      #pragma unroll
      for (int n = 0; n < 4; ++n)
        Crow[n * 16 + lr] = acc[m][n][r];
    }
  }
}

// -------- fp32 -> bf16 convert (4 elems/thread) --------
__global__ __launch_bounds__(256) void f32_to_bf16(const float* __restrict__ in,
                                                   ushort_t* __restrict__ out) {
  const int i = (blockIdx.x * 256 + threadIdx.x) * 4;
  float4 a = *(const float4*)&in[i];
  uint2 p;
  p.x = (unsigned)f2bf(a.x) | ((unsigned)f2bf(a.y) << 16);
  p.y = (unsigned)f2bf(a.z) | ((unsigned)f2bf(a.w) << 16);
  *(uint2*)&out[i] = p;
}

// -------- W (K,N) fp32 -> Wt (N,K) bf16 --------
__global__ __launch_bounds__(256) void wt_bf16(const float* __restrict__ W,
                                               ushort_t* __restrict__ Wt,
                                               int K, int N) {
  __shared__ ushort_t t[32][33];
  const int k0 = blockIdx.y * 32, n0 = blockIdx.x * 32;
  const int i = threadIdx.x;
  const int r = i >> 3, c4 = (i & 7) * 4;
  float4 v = *(const float4*)&W[(size_t)(k0 + r) * N + n0 + c4];
  t[r][c4 + 0] = f2bf(v.x); t[r][c4 + 1] = f2bf(v.y);
  t[r][c4 + 2] = f2bf(v.z); t[r][c4 + 3] = f2bf(v.w);
  __syncthreads();
  ushort_t o0 = t[c4 + 0][r], o1 = t[c4 + 1][r], o2 = t[c4 + 2][r], o3 = t[c4 + 3][r];
  uint2 p;
  p.x = (unsigned)o0 | ((unsigned)o1 << 16);
  p.y = (unsigned)o2 | ((unsigned)o3 << 16);
  *(uint2*)&Wt[(size_t)(n0 + r) * K + k0 + c4] = p;
}

// -------- transform: raw (B,T,2C) fp32 -> packed (B,H,T,128) bf16 --------
__global__ __launch_bounds__(256) void qk_transform(const float* __restrict__ raw,
                                                    ushort_t* __restrict__ out) {
  const int idx = blockIdx.x * 256 + threadIdx.x;   // over B*T*C
  const int c = idx & (C_ - 1);
  const int bt = idx >> 10;
  const int t = bt & (T_ - 1);
  const int b = bt >> 11;
  const int h = c >> 6, d = c & 63;
  float amp = raw[(size_t)bt * 2048 + c];
  float ph  = raw[(size_t)bt * 2048 + 1024 + c];
  float sp = (amp > 20.f) ? amp : log1pf(expf(amp));
  float qc = sp * cosf(ph);
  float qs = sp * sinf(ph);
  size_t o = ((size_t)((b * H_ + h) * T_ + t)) * 128 + d;
  out[o] = f2bf(qc);
  out[o + 64] = f2bf(qs);
}

// -------- V (B,T,C) fp32 -> V^T (B,H,64,T) bf16 --------
__global__ __launch_bounds__(256) void v_transpose(const float* __restrict__ V,
                                                   ushort_t* __restrict__ VT) {
  const int bh = blockIdx.y;
  const int b = bh >> 4, h = bh & 15;
  const int t0 = blockIdx.x * 32;
  __shared__ ushort_t lds[32][72];
  const int i = threadIdx.x;
  {
    int r = i >> 3, d0 = (i & 7) * 8;
    const float* src = V + ((size_t)(b * T_) + t0 + r) * C_ + h * 64 + d0;
    float4 a = *(const float4*)src;
    float4 c = *(const float4*)(src + 4);
    lds[r][d0 + 0] = f2bf(a.x); lds[r][d0 + 1] = f2bf(a.y);
    lds[r][d0 + 2] = f2bf(a.z); lds[r][d0 + 3] = f2bf(a.w);
    lds[r][d0 + 4] = f2bf(c.x); lds[r][d0 + 5] = f2bf(c.y);
    lds[r][d0 + 6] = f2bf(c.z); lds[r][d0 + 7] = f2bf(c.w);
  }
  __syncthreads();
  {
    int d = i >> 2, tq = (i & 3) * 8;
    ushort_t tmp[8];
    #pragma unroll
    for (int j = 0; j < 8; ++j) tmp[j] = lds[tq + j][d];
    ulonglong2 pk;
    pk.x = (unsigned long long)tmp[0] | ((unsigned long long)tmp[1] << 16) |
           ((unsigned long long)tmp[2] << 32) | ((unsigned long long)tmp[3] << 48);
    pk.y = (unsigned long long)tmp[4] | ((unsigned long long)tmp[5] << 16) |
           ((unsigned long long)tmp[6] << 32) | ((unsigned long long)tmp[7] << 48);
    *(ulonglong2*)(VT + ((size_t)bh * 64 + d) * T_ + t0 + tq) = pk;
  }
}

// -------- flash attention, bf16 MFMA, swapped-QK^T lane-local softmax --------
// Q,K: (B*H, T, 128) bf16; VT: (B*H, 64, T) bf16; O: (B,T,C) bf16
__global__ __launch_bounds__(256) void attn_mfma(const ushort_t* __restrict__ Q,
                                                 const ushort_t* __restrict__ K,
                                                 const ushort_t* __restrict__ VT,
                                                 const float* __restrict__ theta,
                                                 ushort_t* __restrict__ O) {
  const int bh = blockIdx.y;
  const int b = bh >> 4, h = bh & 15;
  const int wid = threadIdx.x >> 6, lane = threadIdx.x & 63;
  const int qt = gridDim.x - 1 - blockIdx.x;   // reversed: longest blocks first
  const int q_base = qt * 64 + wid * 16;
  const int lr = lane & 15, lg = lane >> 4;

  const float th = theta[h];
  const int qidx = q_base + lr;

  // Q B-fragments (rows q_base+lr, 4 K-steps of 32 over d=0..127)
  bf16x8 qf[4];
  {
    const ushort_t* Qrow = Q + ((size_t)bh * T_ + qidx) * 128 + lg * 8;
    #pragma unroll
    for (int ks = 0; ks < 4; ++ks) qf[ks] = *(const bf16x8*)(Qrow + ks * 32);
  }

  // gate rank-2 trig. lane owns q-row lr: single cq/sq (SCALE folded in).
  const float cq = cosf(th * (float)qidx * GAMMA_INV) * SCALE;
  const float sq = sinf(th * (float)qidx * GAMMA_INV) * SCALE;
  // key trig for k-local = lg*4+r (r=0..3); +16 derived; advance 32/tile
  float ck[4], sk[4];
  #pragma unroll
  for (int r = 0; r < 4; ++r) {
    float ang = th * (float)(lg * 4 + r) * GAMMA_INV;
    ck[r] = cosf(ang); sk[r] = sinf(ang);
  }
  const float c2 = cosf(th * 2.0f), s2 = sinf(th * 2.0f);   // +16 keys
  const float cd = cosf(th * 4.0f), sd = sinf(th * 4.0f);   // +32 keys

  f32x4 o_acc[4];
  #pragma unroll
  for (int n = 0; n < 4; ++n)
    #pragma unroll
    for (int r = 0; r < 4; ++r) o_acc[n][r] = 0.0f;
  float m_run = -1e30f, l_run = 0.0f;

  const ushort_t* Vbase = VT + (size_t)bh * 64 * T_;
  const int nkt = ((q_base + 15) >> 5) + 1;
  for (int kt = 0; kt < nkt; ++kt) {
    const int k0 = kt * 32;
    // ---- S^T = K @ Q^T: lane holds S[q=lr][k0 + lg*4+r (+16)] ----
    f32x4 s0, s1;
    #pragma unroll
    for (int r = 0; r < 4; ++r) { s0[r] = 0.0f; s1[r] = 0.0f; }
    {
      const ushort_t* Krow0 = K + ((size_t)bh * T_ + k0 + lr) * 128 + lg * 8;
      const ushort_t* Krow1 = Krow0 + 16 * 128;
      #pragma unroll
      for (int ks = 0; ks < 4; ++ks) {
        bf16x8 kf0 = *(const bf16x8*)(Krow0 + ks * 32);
        bf16x8 kf1 = *(const bf16x8*)(Krow1 + ks * 32);
        s0 = mfma16(kf0, qf[ks], s0);   // swapped operands -> S^T
        s1 = mfma16(kf1, qf[ks], s1);
      }
    }
    // ---- gate * scale + causal mask (all in-lane) ----
    float ck16[4], sk16[4], v0[4], v1[4];
    #pragma unroll
    for (int r = 0; r < 4; ++r) {
      ck16[r] = ck[r] * c2 - sk[r] * s2;
      sk16[r] = sk[r] * c2 + ck[r] * s2;
      float g0 = cq * ck[r] + sq * sk[r];
      float g1 = cq * ck16[r] + sq * sk16[r];
      v0[r] = s0[r] * g0;
      v1[r] = s1[r] * g1;
      if (k0 + lg * 4 + r > qidx) v0[r] = -1e30f;
      if (k0 + 16 + lg * 4 + r > qidx) v1[r] = -1e30f;
    }
    // ---- row max: 7 in-lane + 2 shfl ----
    float tm = fmaxf(fmaxf(fmaxf(v0[0], v0[1]), fmaxf(v0[2], v0[3])),
                     fmaxf(fmaxf(v1[0], v1[1]), fmaxf(v1[2], v1[3])));
    tm = fmaxf(tm, __shfl_xor(tm, 16));
    tm = fmaxf(tm, __shfl_xor(tm, 32));
    // ---- defer-max rescale (rare) ----
    if (__ballot(tm > m_run + 8.0f)) {
      float mn = fmaxf(m_run, tm);
      float esc = __expf(m_run - mn);
      m_run = mn;
      l_run *= esc;
      #pragma unroll
      for (int r = 0; r < 4; ++r) {
        float er = __shfl(esc, lg * 4 + r);   // esc of output-row q = lg*4+r
        #pragma unroll
        for (int n = 0; n < 4; ++n) o_acc[n][r] *= er;
      }
    }
    // ---- exp + row sum ----
    float e0[4], e1[4], ps = 0.0f;
    #pragma unroll
    for (int r = 0; r < 4; ++r) {
      e0[r] = __expf(v0[r] - m_run);
      e1[r] = __expf(v1[r] - m_run);
      ps += e0[r] + e1[r];
    }
    ps += __shfl_xor(ps, 16);
    ps += __shfl_xor(ps, 32);
    l_run += ps;
    // ---- pack P (in registers, k-order = [lg*4+0..3, 16+lg*4+0..3]) ----
    bf16x8 pa;
    #pragma unroll
    for (int r = 0; r < 4; ++r) {
      pa[r] = (short)f2bf(e0[r]);
      pa[4 + r] = (short)f2bf(e1[r]);
    }
    // ---- PV: V loaded with the SAME k-permutation (cancels) ----
    #pragma unroll
    for (int n = 0; n < 4; ++n) {
      const ushort_t* vrow = Vbase + (size_t)(n * 16 + lr) * T_ + k0 + lg * 4;
      union { bf16x8 v; uint2 u[2]; } uu;
      uu.u[0] = *(const uint2*)(vrow);
      uu.u[1] = *(const uint2*)(vrow + 16);
      o_acc[n] = mfma16(pa, uu.v, o_acc[n]);
    }
    // ---- advance key trig by 32 keys ----
    #pragma unroll
    for (int r = 0; r < 4; ++r) {
      float t0 = ck[r] * cd - sk[r] * sd;
      sk[r] = sk[r] * cd + ck[r] * sd;
      ck[r] = t0;
    }
  }
  // ---- epilogue: normalize (l of output-row via shfl), store bf16 ----
  #pragma unroll
  for (int r = 0; r < 4; ++r) {
    float lq = __shfl(l_run, lg * 4 + r);
    const float linv = 1.0f / lq;
    const int q = q_base + lg * 4 + r;
    ushort_t* Orow = O + ((size_t)b * T_ + q) * C_ + h * 64;
    #pragma unroll
    for (int n = 0; n < 4; ++n)
      Orow[n * 16 + lr] = f2bf(o_acc[n][r] * linv);
  }
}

} // namespace

extern "C" void kernel_launch(void* const* d_in, const int* in_sizes, int n_in,
                              void* d_out, int out_size, void* d_ws, size_t ws_size,
                              hipStream_t stream) {
  const float* x  = (const float*)d_in[0];
  const float* Wq = (const float*)d_in[1];
  const float* Wk = (const float*)d_in[2];
  const float* Wv = (const float*)d_in[3];
  const float* Wo = (const float*)d_in[4];
  const float* th = (const float*)d_in[5];
  float* out = (float*)d_out;
  float* ws = (float*)d_ws;

  // ---- workspace layout (float offsets; total 22,020,096 floats = 88 MB) ----
  // Qb/Kb = B*H*T*128 bf16 = 8,388,608 elems = 16 MB each.
  float* raw = ws;
  float* Vf  = raw;
  ushort_t* Ob  = (ushort_t*)(ws + 4194304);
  ushort_t* vt  = (ushort_t*)(ws + 6291456);
  ushort_t* Qb  = (ushort_t*)(ws + 8388608);
  ushort_t* Kb  = (ushort_t*)(ws + 12582912);
  ushort_t* xb  = (ushort_t*)(ws + 16777216);
  ushort_t* Wqt = (ushort_t*)(ws + 18874368);
  ushort_t* Wkt = (ushort_t*)(ws + 19922944);
  ushort_t* Wvt = (ushort_t*)(ws + 20971520);
  ushort_t* Wot = (ushort_t*)(ws + 21495808);

  dim3 blk(256);
  f32_to_bf16<<<4096, blk, 0, stream>>>(x, xb);
  wt_bf16<<<dim3(64, 32), blk, 0, stream>>>(Wq, Wqt, 1024, 2048);
  wt_bf16<<<dim3(64, 32), blk, 0, stream>>>(Wk, Wkt, 1024, 2048);
  wt_bf16<<<dim3(32, 32), blk, 0, stream>>>(Wv, Wvt, 1024, 1024);
  wt_bf16<<<dim3(32, 32), blk, 0, stream>>>(Wo, Wot, 1024, 1024);

  gemm_bt<<<dim3(16, 32), blk, 0, stream>>>(xb, Wqt, raw, 2048, 1024);
  qk_transform<<<16384, blk, 0, stream>>>(raw, Qb);
  gemm_bt<<<dim3(16, 32), blk, 0, stream>>>(xb, Wkt, raw, 2048, 1024);
  qk_transform<<<16384, blk, 0, stream>>>(raw, Kb);
  gemm_bt<<<dim3(8, 32), blk, 0, stream>>>(xb, Wvt, Vf, 1024, 1024);
  v_transpose<<<dim3(64, 32), blk, 0, stream>>>(Vf, vt);
  attn_mfma<<<dim3(32, 32), blk, 0, stream>>>(Qb, Kb, vt, th, Ob);
  gemm_bt<<<dim3(8, 32), blk, 0, stream>>>(Ob, Wot, out, 1024, 1024);
}

// Round 7
// 351.096 us; speedup vs baseline: 1.8029x; 1.8029x over previous
//
#include <hip/hip_runtime.h>
#include <cmath>

namespace {

constexpr int B_ = 2, T_ = 2048, C_ = 1024, H_ = 16;
constexpr float GAMMA_INV = 0.125f;   // 1/GAMMA
constexpr float SCALE = 0.125f;       // 1/sqrt(D), D=64

typedef __attribute__((ext_vector_type(8))) short bf16x8;
typedef __attribute__((ext_vector_type(4))) float f32x4;
typedef unsigned short ushort_t;

__device__ __forceinline__ ushort_t f2bf(float x) {
  union { float f; unsigned int u; } v; v.f = x;
  unsigned int r = (v.u + 0x7fffu + ((v.u >> 16) & 1u)) >> 16;
  return (ushort_t)r;
}

__device__ __forceinline__ f32x4 mfma16(bf16x8 a, bf16x8 b, f32x4 c) {
  return __builtin_amdgcn_mfma_f32_16x16x32_bf16(a, b, c, 0, 0, 0);
}

// ---------------- bf16 MFMA GEMM, register-staged LDS ----------------
constexpr int GBM = 128, GBN = 128, GBK = 32;
constexpr int LDP = 40;

__global__ __launch_bounds__(256) void gemm_bt(const ushort_t* __restrict__ A,
                                               const ushort_t* __restrict__ Bt,
                                               float* __restrict__ Cm,
                                               int N, int K) {
  __shared__ alignas(16) ushort_t As[GBM][LDP];
  __shared__ alignas(16) ushort_t Bs[GBN][LDP];
  const int tid = threadIdx.x;
  const int m0 = blockIdx.y * GBM, n0 = blockIdx.x * GBN;
  const int wv = tid >> 6;
  const int ln = tid & 63;
  const int lr = ln & 15, hi = ln >> 4;
  const int wr = wv >> 1, wc = wv & 1;

  const int sr0 = tid >> 2, sc0 = (tid & 3) * 8;
  const int sr1 = sr0 + 64;
  const ushort_t* gA0 = A + (size_t)(m0 + sr0) * K + sc0;
  const ushort_t* gA1 = A + (size_t)(m0 + sr1) * K + sc0;
  const ushort_t* gB0 = Bt + (size_t)(n0 + sr0) * K + sc0;
  const ushort_t* gB1 = Bt + (size_t)(n0 + sr1) * K + sc0;

  f32x4 acc[4][4];
  #pragma unroll
  for (int m = 0; m < 4; ++m)
    #pragma unroll
    for (int n = 0; n < 4; ++n)
      #pragma unroll
      for (int r = 0; r < 4; ++r) acc[m][n][r] = 0.0f;

  for (int k0 = 0; k0 < K; k0 += GBK) {
    uint4 a0 = *(const uint4*)(gA0 + k0);
    uint4 a1 = *(const uint4*)(gA1 + k0);
    uint4 b0 = *(const uint4*)(gB0 + k0);
    uint4 b1 = *(const uint4*)(gB1 + k0);
    *(uint4*)&As[sr0][sc0] = a0;
    *(uint4*)&As[sr1][sc0] = a1;
    *(uint4*)&Bs[sr0][sc0] = b0;
    *(uint4*)&Bs[sr1][sc0] = b1;
    __syncthreads();
    bf16x8 af[4], bfr[4];
    #pragma unroll
    for (int m = 0; m < 4; ++m)
      af[m] = *(const bf16x8*)&As[wr * 64 + m * 16 + lr][hi * 8];
    #pragma unroll
    for (int n = 0; n < 4; ++n)
      bfr[n] = *(const bf16x8*)&Bs[wc * 64 + n * 16 + lr][hi * 8];
    #pragma unroll
    for (int m = 0; m < 4; ++m)
      #pragma unroll
      for (int n = 0; n < 4; ++n)
        acc[m][n] = mfma16(af[m], bfr[n], acc[m][n]);
    __syncthreads();
  }
  #pragma unroll
  for (int m = 0; m < 4; ++m) {
    #pragma unroll
    for (int r = 0; r < 4; ++r) {
      const int row = m0 + wr * 64 + m * 16 + hi * 4 + r;
      float* Crow = Cm + (size_t)row * N + n0 + wc * 64;
      #pragma unroll
      for (int n = 0; n < 4; ++n)
        Crow[n * 16 + lr] = acc[m][n][r];
    }
  }
}

// -------- fp32 -> bf16 convert --------
__global__ __launch_bounds__(256) void f32_to_bf16(const float* __restrict__ in,
                                                   ushort_t* __restrict__ out) {
  const int i = (blockIdx.x * 256 + threadIdx.x) * 4;
  float4 a = *(const float4*)&in[i];
  uint2 p;
  p.x = (unsigned)f2bf(a.x) | ((unsigned)f2bf(a.y) << 16);
  p.y = (unsigned)f2bf(a.z) | ((unsigned)f2bf(a.w) << 16);
  *(uint2*)&out[i] = p;
}

// -------- W (K,N) fp32 -> Wt (N,K) bf16 --------
__global__ __launch_bounds__(256) void wt_bf16(const float* __restrict__ W,
                                               ushort_t* __restrict__ Wt,
                                               int K, int N) {
  __shared__ ushort_t t[32][33];
  const int k0 = blockIdx.y * 32, n0 = blockIdx.x * 32;
  const int i = threadIdx.x;
  const int r = i >> 3, c4 = (i & 7) * 4;
  float4 v = *(const float4*)&W[(size_t)(k0 + r) * N + n0 + c4];
  t[r][c4 + 0] = f2bf(v.x); t[r][c4 + 1] = f2bf(v.y);
  t[r][c4 + 2] = f2bf(v.z); t[r][c4 + 3] = f2bf(v.w);
  __syncthreads();
  ushort_t o0 = t[c4 + 0][r], o1 = t[c4 + 1][r], o2 = t[c4 + 2][r], o3 = t[c4 + 3][r];
  uint2 p;
  p.x = (unsigned)o0 | ((unsigned)o1 << 16);
  p.y = (unsigned)o2 | ((unsigned)o3 << 16);
  *(uint2*)&Wt[(size_t)(n0 + r) * K + k0 + c4] = p;
}

// -------- transform: raw (B,T,2C) fp32 -> packed (B,H,T,128) bf16 --------
__global__ __launch_bounds__(256) void qk_transform(const float* __restrict__ raw,
                                                    ushort_t* __restrict__ out) {
  const int idx = blockIdx.x * 256 + threadIdx.x;
  const int c = idx & (C_ - 1);
  const int bt = idx >> 10;
  const int t = bt & (T_ - 1);
  const int b = bt >> 11;
  const int h = c >> 6, d = c & 63;
  float amp = raw[(size_t)bt * 2048 + c];
  float ph  = raw[(size_t)bt * 2048 + 1024 + c];
  float sp = (amp > 20.f) ? amp : log1pf(expf(amp));
  float qc = sp * cosf(ph);
  float qs = sp * sinf(ph);
  size_t o = ((size_t)((b * H_ + h) * T_ + t)) * 128 + d;
  out[o] = f2bf(qc);
  out[o + 64] = f2bf(qs);
}

// -------- V (B,T,C) fp32 -> V^T (B,H,64,T) bf16 --------
__global__ __launch_bounds__(256) void v_transpose(const float* __restrict__ V,
                                                   ushort_t* __restrict__ VT) {
  const int bh = blockIdx.y;
  const int b = bh >> 4, h = bh & 15;
  const int t0 = blockIdx.x * 32;
  __shared__ ushort_t lds[32][72];
  const int i = threadIdx.x;
  {
    int r = i >> 3, d0 = (i & 7) * 8;
    const float* src = V + ((size_t)(b * T_) + t0 + r) * C_ + h * 64 + d0;
    float4 a = *(const float4*)src;
    float4 c = *(const float4*)(src + 4);
    lds[r][d0 + 0] = f2bf(a.x); lds[r][d0 + 1] = f2bf(a.y);
    lds[r][d0 + 2] = f2bf(a.z); lds[r][d0 + 3] = f2bf(a.w);
    lds[r][d0 + 4] = f2bf(c.x); lds[r][d0 + 5] = f2bf(c.y);
    lds[r][d0 + 6] = f2bf(c.z); lds[r][d0 + 7] = f2bf(c.w);
  }
  __syncthreads();
  {
    int d = i >> 2, tq = (i & 3) * 8;
    ushort_t tmp[8];
    #pragma unroll
    for (int j = 0; j < 8; ++j) tmp[j] = lds[tq + j][d];
    ulonglong2 pk;
    pk.x = (unsigned long long)tmp[0] | ((unsigned long long)tmp[1] << 16) |
           ((unsigned long long)tmp[2] << 32) | ((unsigned long long)tmp[3] << 48);
    pk.y = (unsigned long long)tmp[4] | ((unsigned long long)tmp[5] << 16) |
           ((unsigned long long)tmp[6] << 32) | ((unsigned long long)tmp[7] << 48);
    *(ulonglong2*)(VT + ((size_t)bh * 64 + d) * T_ + t0 + tq) = pk;
  }
}

// -------- flash attention: LDS-staged K/V, double-buffered, XOR-swizzled --------
// Q,K: (B*H, T, 128) bf16; VT: (B*H, 64, T) bf16; O: (B,T,C) bf16
// 1D grid of 1024 blocks; decode: xcd=id&7, bh=xcd*4+(sub>>5), qc=31-(sub&31)
__global__ __launch_bounds__(256) void attn_mfma(const ushort_t* __restrict__ Q,
                                                 const ushort_t* __restrict__ K,
                                                 const ushort_t* __restrict__ VT,
                                                 const float* __restrict__ theta,
                                                 ushort_t* __restrict__ O) {
  const int id = blockIdx.x;
  const int xcd = id & 7, sub = id >> 3;
  const int bh = xcd * 4 + (sub >> 5);
  const int qc = 31 - (sub & 31);
  const int b = bh >> 4, h = bh & 15;
  const int tid = threadIdx.x;
  const int wid = tid >> 6, lane = tid & 63;
  const int q_base = qc * 64 + wid * 16;
  const int lr = lane & 15, lg = lane >> 4;
  const int kx = (lr & 7) << 4;          // read-side XOR (row&7 == lr&7 for rows j*16+lr)

  // LDS: K tile 64x128 bf16 (16KB), V tile 64x64 bf16 (8KB), double-buffered = 48KB
  __shared__ alignas(16) ushort_t Ksh[2][64 * 128];
  __shared__ alignas(16) ushort_t Vsh[2][64 * 64];

  const float th = theta[h];
  const int qidx = q_base + lr;

  // Q B-fragments
  bf16x8 qf[4];
  {
    const ushort_t* Qrow = Q + ((size_t)bh * T_ + qidx) * 128 + lg * 8;
    #pragma unroll
    for (int ks = 0; ks < 4; ++ks) qf[ks] = *(const bf16x8*)(Qrow + ks * 32);
  }

  // gate rank-2 trig: gate(j,r) = Aj[j]*ck[r] + Bj[j]*sk[r], SCALE folded into Aj/Bj
  const float cq = cosf(th * (float)qidx * GAMMA_INV) * SCALE;
  const float sq = sinf(th * (float)qidx * GAMMA_INV) * SCALE;
  float ck[4], sk[4];
  #pragma unroll
  for (int r = 0; r < 4; ++r) {
    float ang = th * (float)(lg * 4 + r) * GAMMA_INV;
    ck[r] = cosf(ang); sk[r] = sinf(ang);
  }
  float Aj[4], Bj[4];
  {
    const float c2 = cosf(th * 2.0f), s2 = sinf(th * 2.0f);
    float cj = 1.0f, sj = 0.0f;
    #pragma unroll
    for (int j = 0; j < 4; ++j) {
      Aj[j] = cq * cj + sq * sj;
      Bj[j] = sq * cj - cq * sj;
      float t0 = cj * c2 - sj * s2;
      sj = sj * c2 + cj * s2;
      cj = t0;
    }
  }
  const float cd8 = cosf(th * 8.0f), sd8 = sinf(th * 8.0f);   // +64 keys

  f32x4 o_acc[4];
  #pragma unroll
  for (int n = 0; n < 4; ++n)
    #pragma unroll
    for (int r = 0; r < 4; ++r) o_acc[n][r] = 0.0f;
  float m_run = -1e30f, l_run = 0.0f;

  // staging thread map
  const int kr = tid >> 2;                 // K row 0..63
  const int kce = (tid & 3) * 32;          // K elem offset (64B = 32 elems)
  const int vd = tid >> 2;                 // V d-row 0..63
  const int vce = (tid & 3) * 16;          // V elem offset (32B = 16 elems)
  const ushort_t* Kgb = K + ((size_t)bh * T_ + kr) * 128 + kce;
  const ushort_t* Vgb = VT + ((size_t)bh * 64 + vd) * T_ + vce;
  uint4 kreg[4], vreg[2];

  const int nkt = qc + 1;

  // ---- prologue: stage tile 0 ----
  {
    #pragma unroll
    for (int c = 0; c < 4; ++c) kreg[c] = *(const uint4*)(Kgb + c * 8);
    #pragma unroll
    for (int c = 0; c < 2; ++c) vreg[c] = *(const uint4*)(Vgb + c * 8);
    #pragma unroll
    for (int c = 0; c < 4; ++c) {
      int byte = (kce * 2 + c * 16) ^ ((kr & 7) << 4);
      *(uint4*)&Ksh[0][kr * 128 + (byte >> 1)] = kreg[c];
    }
    #pragma unroll
    for (int c = 0; c < 2; ++c) {
      int byte = (vce * 2 + c * 16) ^ ((vd & 7) << 4);
      *(uint4*)&Vsh[0][vd * 64 + (byte >> 1)] = vreg[c];
    }
  }
  __syncthreads();

  for (int kt = 0; kt < nkt; ++kt) {
    const int cur = kt & 1;
    const int k0 = kt * 64;
    const bool more = (kt + 1) < nkt;
    // ---- prefetch next tile (global -> regs), hidden under compute ----
    if (more) {
      const int koff = (kt + 1) * 64;
      #pragma unroll
      for (int c = 0; c < 4; ++c) kreg[c] = *(const uint4*)(Kgb + (size_t)koff * 128 + c * 8);
      #pragma unroll
      for (int c = 0; c < 2; ++c) vreg[c] = *(const uint4*)(Vgb + koff + c * 8);
    }
    // ---- S = K @ Q^T from LDS ----
    f32x4 s[4];
    #pragma unroll
    for (int j = 0; j < 4; ++j) {
      #pragma unroll
      for (int r = 0; r < 4; ++r) s[j][r] = 0.0f;
    }
    #pragma unroll
    for (int j = 0; j < 4; ++j) {
      const int rbase = (j * 16 + lr) * 128;
      #pragma unroll
      for (int ks = 0; ks < 4; ++ks) {
        const int byte = (ks * 64 + lg * 16) ^ kx;
        bf16x8 kf = *(const bf16x8*)&Ksh[cur][rbase + (byte >> 1)];
        s[j] = mfma16(kf, qf[ks], s[j]);
      }
    }
    // ---- gate + causal mask ----
    float v[4][4];
    #pragma unroll
    for (int j = 0; j < 4; ++j)
      #pragma unroll
      for (int r = 0; r < 4; ++r) {
        float g = Aj[j] * ck[r] + Bj[j] * sk[r];
        float x = s[j][r] * g;
        if (k0 + j * 16 + lg * 4 + r > qidx) x = -1e30f;
        v[j][r] = x;
      }
    // ---- row max (15 in-lane + 2 shfl) ----
    float tm = v[0][0];
    #pragma unroll
    for (int j = 0; j < 4; ++j)
      #pragma unroll
      for (int r = 0; r < 4; ++r) tm = fmaxf(tm, v[j][r]);
    tm = fmaxf(tm, __shfl_xor(tm, 16));
    tm = fmaxf(tm, __shfl_xor(tm, 32));
    // ---- defer-max rescale (rare) ----
    if (__ballot(tm > m_run + 8.0f)) {
      float mn = fmaxf(m_run, tm);
      float esc = __expf(m_run - mn);
      m_run = mn;
      l_run *= esc;
      #pragma unroll
      for (int r = 0; r < 4; ++r) {
        float er = __shfl(esc, lg * 4 + r);
        #pragma unroll
        for (int n = 0; n < 4; ++n) o_acc[n][r] *= er;
      }
    }
    // ---- exp + row sum ----
    float e[4][4], ps = 0.0f;
    #pragma unroll
    for (int j = 0; j < 4; ++j)
      #pragma unroll
      for (int r = 0; r < 4; ++r) {
        e[j][r] = __expf(v[j][r] - m_run);
        ps += e[j][r];
      }
    ps += __shfl_xor(ps, 16);
    ps += __shfl_xor(ps, 32);
    l_run += ps;
    // ---- pack P: pa[h] = [e[2h][0..3], e[2h+1][0..3]] ----
    bf16x8 pa[2];
    #pragma unroll
    for (int hh = 0; hh < 2; ++hh)
      #pragma unroll
      for (int r = 0; r < 4; ++r) {
        pa[hh][r] = (short)f2bf(e[2 * hh][r]);
        pa[hh][4 + r] = (short)f2bf(e[2 * hh + 1][r]);
      }
    // ---- PV from LDS (same k-permutation on V) ----
    #pragma unroll
    for (int n = 0; n < 4; ++n) {
      const int dbase = (n * 16 + lr) * 64;
      #pragma unroll
      for (int hh = 0; hh < 2; ++hh) {
        const int b0 = (hh * 64 + lg * 8) ^ kx;
        const int b1 = (hh * 64 + 32 + lg * 8) ^ kx;
        union { bf16x8 v8; uint2 u[2]; } uu;
        uu.u[0] = *(const uint2*)&Vsh[cur][dbase + (b0 >> 1)];
        uu.u[1] = *(const uint2*)&Vsh[cur][dbase + (b1 >> 1)];
        o_acc[n] = mfma16(pa[hh], uu.v8, o_acc[n]);
      }
    }
    // ---- advance key trig by 64 keys ----
    #pragma unroll
    for (int r = 0; r < 4; ++r) {
      float t0 = ck[r] * cd8 - sk[r] * sd8;
      sk[r] = sk[r] * cd8 + ck[r] * sd8;
      ck[r] = t0;
    }
    // ---- publish prefetched tile ----
    __syncthreads();
    if (more) {
      const int nb = cur ^ 1;
      #pragma unroll
      for (int c = 0; c < 4; ++c) {
        int byte = (kce * 2 + c * 16) ^ ((kr & 7) << 4);
        *(uint4*)&Ksh[nb][kr * 128 + (byte >> 1)] = kreg[c];
      }
      #pragma unroll
      for (int c = 0; c < 2; ++c) {
        int byte = (vce * 2 + c * 16) ^ ((vd & 7) << 4);
        *(uint4*)&Vsh[nb][vd * 64 + (byte >> 1)] = vreg[c];
      }
      __syncthreads();
    }
  }
  // ---- epilogue ----
  #pragma unroll
  for (int r = 0; r < 4; ++r) {
    float lq = __shfl(l_run, lg * 4 + r);
    const float linv = 1.0f / lq;
    const int q = q_base + lg * 4 + r;
    ushort_t* Orow = O + ((size_t)b * T_ + q) * C_ + h * 64;
    #pragma unroll
    for (int n = 0; n < 4; ++n)
      Orow[n * 16 + lr] = f2bf(o_acc[n][r] * linv);
  }
}

} // namespace

extern "C" void kernel_launch(void* const* d_in, const int* in_sizes, int n_in,
                              void* d_out, int out_size, void* d_ws, size_t ws_size,
                              hipStream_t stream) {
  const float* x  = (const float*)d_in[0];
  const float* Wq = (const float*)d_in[1];
  const float* Wk = (const float*)d_in[2];
  const float* Wv = (const float*)d_in[3];
  const float* Wo = (const float*)d_in[4];
  const float* th = (const float*)d_in[5];
  float* out = (float*)d_out;
  float* ws = (float*)d_ws;

  // ---- workspace layout (float offsets; total 22,020,096 floats = 88 MB) ----
  float* raw = ws;
  float* Vf  = raw;
  ushort_t* Ob  = (ushort_t*)(ws + 4194304);
  ushort_t* vt  = (ushort_t*)(ws + 6291456);
  ushort_t* Qb  = (ushort_t*)(ws + 8388608);
  ushort_t* Kb  = (ushort_t*)(ws + 12582912);
  ushort_t* xb  = (ushort_t*)(ws + 16777216);
  ushort_t* Wqt = (ushort_t*)(ws + 18874368);
  ushort_t* Wkt = (ushort_t*)(ws + 19922944);
  ushort_t* Wvt = (ushort_t*)(ws + 20971520);
  ushort_t* Wot = (ushort_t*)(ws + 21495808);

  dim3 blk(256);
  f32_to_bf16<<<4096, blk, 0, stream>>>(x, xb);
  wt_bf16<<<dim3(64, 32), blk, 0, stream>>>(Wq, Wqt, 1024, 2048);
  wt_bf16<<<dim3(64, 32), blk, 0, stream>>>(Wk, Wkt, 1024, 2048);
  wt_bf16<<<dim3(32, 32), blk, 0, stream>>>(Wv, Wvt, 1024, 1024);
  wt_bf16<<<dim3(32, 32), blk, 0, stream>>>(Wo, Wot, 1024, 1024);

  gemm_bt<<<dim3(16, 32), blk, 0, stream>>>(xb, Wqt, raw, 2048, 1024);
  qk_transform<<<16384, blk, 0, stream>>>(raw, Qb);
  gemm_bt<<<dim3(16, 32), blk, 0, stream>>>(xb, Wkt, raw, 2048, 1024);
  qk_transform<<<16384, blk, 0, stream>>>(raw, Kb);
  gemm_bt<<<dim3(8, 32), blk, 0, stream>>>(xb, Wvt, Vf, 1024, 1024);
  v_transpose<<<dim3(64, 32), blk, 0, stream>>>(Vf, vt);
  attn_mfma<<<1024, blk, 0, stream>>>(Qb, Kb, vt, th, Ob);
  gemm_bt<<<dim3(8, 32), blk, 0, stream>>>(Ob, Wot, out, 1024, 1024);
}

// Round 8
// 320.995 us; speedup vs baseline: 1.9720x; 1.0938x over previous
//
#include <hip/hip_runtime.h>
#include <cmath>

namespace {

constexpr int B_ = 2, T_ = 2048, C_ = 1024, H_ = 16;
constexpr float GAMMA_INV = 0.125f;   // 1/GAMMA
constexpr float SCALE = 0.125f;       // 1/sqrt(D), D=64

typedef __attribute__((ext_vector_type(8))) short bf16x8;
typedef __attribute__((ext_vector_type(4))) float f32x4;
typedef unsigned short ushort_t;

__device__ __forceinline__ ushort_t f2bf(float x) {
  union { float f; unsigned int u; } v; v.f = x;
  unsigned int r = (v.u + 0x7fffu + ((v.u >> 16) & 1u)) >> 16;
  return (ushort_t)r;
}

__device__ __forceinline__ unsigned pk_bf16(float a, float b) {
  unsigned r;
  asm("v_cvt_pk_bf16_f32 %0, %1, %2" : "=v"(r) : "v"(a), "v"(b));
  return r;
}

__device__ __forceinline__ f32x4 mfma16(bf16x8 a, bf16x8 b, f32x4 c) {
  return __builtin_amdgcn_mfma_f32_16x16x32_bf16(a, b, c, 0, 0, 0);
}

// ---------------- bf16 MFMA GEMM, register-staged LDS ----------------
constexpr int GBM = 128, GBN = 128, GBK = 32;
constexpr int LDP = 40;

__global__ __launch_bounds__(256) void gemm_bt(const ushort_t* __restrict__ A,
                                               const ushort_t* __restrict__ Bt,
                                               float* __restrict__ Cm,
                                               int N, int K) {
  __shared__ alignas(16) ushort_t As[GBM][LDP];
  __shared__ alignas(16) ushort_t Bs[GBN][LDP];
  const int tid = threadIdx.x;
  const int m0 = blockIdx.y * GBM, n0 = blockIdx.x * GBN;
  const int wv = tid >> 6;
  const int ln = tid & 63;
  const int lr = ln & 15, hi = ln >> 4;
  const int wr = wv >> 1, wc = wv & 1;

  const int sr0 = tid >> 2, sc0 = (tid & 3) * 8;
  const int sr1 = sr0 + 64;
  const ushort_t* gA0 = A + (size_t)(m0 + sr0) * K + sc0;
  const ushort_t* gA1 = A + (size_t)(m0 + sr1) * K + sc0;
  const ushort_t* gB0 = Bt + (size_t)(n0 + sr0) * K + sc0;
  const ushort_t* gB1 = Bt + (size_t)(n0 + sr1) * K + sc0;

  f32x4 acc[4][4];
  #pragma unroll
  for (int m = 0; m < 4; ++m)
    #pragma unroll
    for (int n = 0; n < 4; ++n)
      #pragma unroll
      for (int r = 0; r < 4; ++r) acc[m][n][r] = 0.0f;

  for (int k0 = 0; k0 < K; k0 += GBK) {
    uint4 a0 = *(const uint4*)(gA0 + k0);
    uint4 a1 = *(const uint4*)(gA1 + k0);
    uint4 b0 = *(const uint4*)(gB0 + k0);
    uint4 b1 = *(const uint4*)(gB1 + k0);
    *(uint4*)&As[sr0][sc0] = a0;
    *(uint4*)&As[sr1][sc0] = a1;
    *(uint4*)&Bs[sr0][sc0] = b0;
    *(uint4*)&Bs[sr1][sc0] = b1;
    __syncthreads();
    bf16x8 af[4], bfr[4];
    #pragma unroll
    for (int m = 0; m < 4; ++m)
      af[m] = *(const bf16x8*)&As[wr * 64 + m * 16 + lr][hi * 8];
    #pragma unroll
    for (int n = 0; n < 4; ++n)
      bfr[n] = *(const bf16x8*)&Bs[wc * 64 + n * 16 + lr][hi * 8];
    #pragma unroll
    for (int m = 0; m < 4; ++m)
      #pragma unroll
      for (int n = 0; n < 4; ++n)
        acc[m][n] = mfma16(af[m], bfr[n], acc[m][n]);
    __syncthreads();
  }
  #pragma unroll
  for (int m = 0; m < 4; ++m) {
    #pragma unroll
    for (int r = 0; r < 4; ++r) {
      const int row = m0 + wr * 64 + m * 16 + hi * 4 + r;
      float* Crow = Cm + (size_t)row * N + n0 + wc * 64;
      #pragma unroll
      for (int n = 0; n < 4; ++n)
        Crow[n * 16 + lr] = acc[m][n][r];
    }
  }
}

// -------- fp32 -> bf16 convert --------
__global__ __launch_bounds__(256) void f32_to_bf16(const float* __restrict__ in,
                                                   ushort_t* __restrict__ out) {
  const int i = (blockIdx.x * 256 + threadIdx.x) * 4;
  float4 a = *(const float4*)&in[i];
  uint2 p;
  p.x = (unsigned)f2bf(a.x) | ((unsigned)f2bf(a.y) << 16);
  p.y = (unsigned)f2bf(a.z) | ((unsigned)f2bf(a.w) << 16);
  *(uint2*)&out[i] = p;
}

// -------- W (K,N) fp32 -> Wt (N,K) bf16 --------
__global__ __launch_bounds__(256) void wt_bf16(const float* __restrict__ W,
                                               ushort_t* __restrict__ Wt,
                                               int K, int N) {
  __shared__ ushort_t t[32][33];
  const int k0 = blockIdx.y * 32, n0 = blockIdx.x * 32;
  const int i = threadIdx.x;
  const int r = i >> 3, c4 = (i & 7) * 4;
  float4 v = *(const float4*)&W[(size_t)(k0 + r) * N + n0 + c4];
  t[r][c4 + 0] = f2bf(v.x); t[r][c4 + 1] = f2bf(v.y);
  t[r][c4 + 2] = f2bf(v.z); t[r][c4 + 3] = f2bf(v.w);
  __syncthreads();
  ushort_t o0 = t[c4 + 0][r], o1 = t[c4 + 1][r], o2 = t[c4 + 2][r], o3 = t[c4 + 3][r];
  uint2 p;
  p.x = (unsigned)o0 | ((unsigned)o1 << 16);
  p.y = (unsigned)o2 | ((unsigned)o3 << 16);
  *(uint2*)&Wt[(size_t)(n0 + r) * K + k0 + c4] = p;
}

// -------- transform: raw (B,T,2C) fp32 -> packed (B,H,T,128) bf16 --------
__global__ __launch_bounds__(256) void qk_transform(const float* __restrict__ raw,
                                                    ushort_t* __restrict__ out) {
  const int idx = blockIdx.x * 256 + threadIdx.x;
  const int c = idx & (C_ - 1);
  const int bt = idx >> 10;
  const int t = bt & (T_ - 1);
  const int b = bt >> 11;
  const int h = c >> 6, d = c & 63;
  float amp = raw[(size_t)bt * 2048 + c];
  float ph  = raw[(size_t)bt * 2048 + 1024 + c];
  float sp = (amp > 20.f) ? amp : log1pf(expf(amp));
  float qc = sp * cosf(ph);
  float qs = sp * sinf(ph);
  size_t o = ((size_t)((b * H_ + h) * T_ + t)) * 128 + d;
  out[o] = f2bf(qc);
  out[o + 64] = f2bf(qs);
}

// -------- V (B,T,C) fp32 -> V^T (B,H,64,T) bf16 --------
__global__ __launch_bounds__(256) void v_transpose(const float* __restrict__ V,
                                                   ushort_t* __restrict__ VT) {
  const int bh = blockIdx.y;
  const int b = bh >> 4, h = bh & 15;
  const int t0 = blockIdx.x * 32;
  __shared__ ushort_t lds[32][72];
  const int i = threadIdx.x;
  {
    int r = i >> 3, d0 = (i & 7) * 8;
    const float* src = V + ((size_t)(b * T_) + t0 + r) * C_ + h * 64 + d0;
    float4 a = *(const float4*)src;
    float4 c = *(const float4*)(src + 4);
    lds[r][d0 + 0] = f2bf(a.x); lds[r][d0 + 1] = f2bf(a.y);
    lds[r][d0 + 2] = f2bf(a.z); lds[r][d0 + 3] = f2bf(a.w);
    lds[r][d0 + 4] = f2bf(c.x); lds[r][d0 + 5] = f2bf(c.y);
    lds[r][d0 + 6] = f2bf(c.z); lds[r][d0 + 7] = f2bf(c.w);
  }
  __syncthreads();
  {
    int d = i >> 2, tq = (i & 3) * 8;
    ushort_t tmp[8];
    #pragma unroll
    for (int j = 0; j < 8; ++j) tmp[j] = lds[tq + j][d];
    ulonglong2 pk;
    pk.x = (unsigned long long)tmp[0] | ((unsigned long long)tmp[1] << 16) |
           ((unsigned long long)tmp[2] << 32) | ((unsigned long long)tmp[3] << 48);
    pk.y = (unsigned long long)tmp[4] | ((unsigned long long)tmp[5] << 16) |
           ((unsigned long long)tmp[6] << 32) | ((unsigned long long)tmp[7] << 48);
    *(ulonglong2*)(VT + ((size_t)bh * 64 + d) * T_ + t0 + tq) = pk;
  }
}

// -------- flash attention: QBLK=128 (32 q-rows/wave), LDS K/V dbuf, swizzled --------
// Q,K: (B*H, T, 128) bf16; VT: (B*H, 64, T) bf16; O: (B,T,C) bf16
// grid 512: xcd=id&7, sub=id>>3: bh=xcd*4+(sub>>4), qc=15-(sub&15)
__global__ __launch_bounds__(256) void attn_mfma(const ushort_t* __restrict__ Q,
                                                 const ushort_t* __restrict__ K,
                                                 const ushort_t* __restrict__ VT,
                                                 const float* __restrict__ theta,
                                                 ushort_t* __restrict__ O) {
  const int id = blockIdx.x;
  const int xcd = id & 7, sub = id >> 3;
  const int bh = xcd * 4 + (sub >> 4);
  const int qc = 15 - (sub & 15);
  const int b = bh >> 4, h = bh & 15;
  const int tid = threadIdx.x;
  const int wid = tid >> 6, lane = tid & 63;
  const int q_base = qc * 128 + wid * 32;     // wave owns rows q_base..q_base+31
  const int lr = lane & 15, lg = lane >> 4;
  const int kx = (lr & 7) << 4;

  __shared__ alignas(16) ushort_t Ksh[2][64 * 128];
  __shared__ alignas(16) ushort_t Vsh[2][64 * 64];

  const float th = theta[h];
  const int q_lo = q_base + lr;
  const int q_hi = q_base + 16 + lr;

  // Q B-fragments for both subtiles
  bf16x8 qfl[4], qfh[4];
  {
    const ushort_t* Qrow = Q + ((size_t)bh * T_ + q_lo) * 128 + lg * 8;
    #pragma unroll
    for (int ks = 0; ks < 4; ++ks) {
      qfl[ks] = *(const bf16x8*)(Qrow + ks * 32);
      qfh[ks] = *(const bf16x8*)(Qrow + 16 * 128 + ks * 32);
    }
  }

  // gate rank-2 trig
  const float cql = cosf(th * (float)q_lo * GAMMA_INV) * SCALE;
  const float sql = sinf(th * (float)q_lo * GAMMA_INV) * SCALE;
  const float cqh = cosf(th * (float)q_hi * GAMMA_INV) * SCALE;
  const float sqh = sinf(th * (float)q_hi * GAMMA_INV) * SCALE;
  float ck[4], sk[4];
  #pragma unroll
  for (int r = 0; r < 4; ++r) {
    float ang = th * (float)(lg * 4 + r) * GAMMA_INV;
    ck[r] = cosf(ang); sk[r] = sinf(ang);
  }
  float Ajl[4], Bjl[4], Ajh[4], Bjh[4];
  {
    const float c2 = cosf(th * 2.0f), s2 = sinf(th * 2.0f);
    float cj = 1.0f, sj = 0.0f;
    #pragma unroll
    for (int j = 0; j < 4; ++j) {
      Ajl[j] = cql * cj + sql * sj;
      Bjl[j] = sql * cj - cql * sj;
      Ajh[j] = cqh * cj + sqh * sj;
      Bjh[j] = sqh * cj - cqh * sj;
      float t0 = cj * c2 - sj * s2;
      sj = sj * c2 + cj * s2;
      cj = t0;
    }
  }
  const float cd8 = cosf(th * 8.0f), sd8 = sinf(th * 8.0f);

  f32x4 o_lo[4], o_hi[4];
  #pragma unroll
  for (int n = 0; n < 4; ++n)
    #pragma unroll
    for (int r = 0; r < 4; ++r) { o_lo[n][r] = 0.0f; o_hi[n][r] = 0.0f; }
  float m_lo = -1e30f, l_lo = 0.0f, m_hi = -1e30f, l_hi = 0.0f;

  // staging thread map (256 threads)
  const int kr = tid >> 2;
  const int kce = (tid & 3) * 32;
  const int vd = tid >> 2;
  const int vce = (tid & 3) * 16;
  const ushort_t* Kgb = K + ((size_t)bh * T_ + kr) * 128 + kce;
  const ushort_t* Vgb = VT + ((size_t)bh * 64 + vd) * T_ + vce;
  uint4 kreg[4], vreg[2];

  const int nkt = 2 * qc + 2;

  {
    #pragma unroll
    for (int c = 0; c < 4; ++c) kreg[c] = *(const uint4*)(Kgb + c * 8);
    #pragma unroll
    for (int c = 0; c < 2; ++c) vreg[c] = *(const uint4*)(Vgb + c * 8);
    #pragma unroll
    for (int c = 0; c < 4; ++c) {
      int byte = (kce * 2 + c * 16) ^ ((kr & 7) << 4);
      *(uint4*)&Ksh[0][kr * 128 + (byte >> 1)] = kreg[c];
    }
    #pragma unroll
    for (int c = 0; c < 2; ++c) {
      int byte = (vce * 2 + c * 16) ^ ((vd & 7) << 4);
      *(uint4*)&Vsh[0][vd * 64 + (byte >> 1)] = vreg[c];
    }
  }
  __syncthreads();

  for (int kt = 0; kt < nkt; ++kt) {
    const int cur = kt & 1;
    const int k0 = kt * 64;
    const bool more = (kt + 1) < nkt;
    if (more) {
      const int koff = (kt + 1) * 64;
      #pragma unroll
      for (int c = 0; c < 4; ++c) kreg[c] = *(const uint4*)(Kgb + (size_t)koff * 128 + c * 8);
      #pragma unroll
      for (int c = 0; c < 2; ++c) vreg[c] = *(const uint4*)(Vgb + koff + c * 8);
    }
    // ---- S = K @ Q^T from LDS: kf shared by lo/hi subtiles ----
    f32x4 sl[4], sh[4];
    #pragma unroll
    for (int j = 0; j < 4; ++j)
      #pragma unroll
      for (int r = 0; r < 4; ++r) { sl[j][r] = 0.0f; sh[j][r] = 0.0f; }
    #pragma unroll
    for (int j = 0; j < 4; ++j) {
      const int rbase = (j * 16 + lr) * 128;
      #pragma unroll
      for (int ks = 0; ks < 4; ++ks) {
        const int byte = (ks * 64 + lg * 16) ^ kx;
        bf16x8 kf = *(const bf16x8*)&Ksh[cur][rbase + (byte >> 1)];
        sl[j] = mfma16(kf, qfl[ks], sl[j]);
        sh[j] = mfma16(kf, qfh[ks], sh[j]);
      }
    }
    // ---- gate + causal mask ----
    float vl[4][4], vh[4][4];
    #pragma unroll
    for (int j = 0; j < 4; ++j)
      #pragma unroll
      for (int r = 0; r < 4; ++r) {
        const int kk = k0 + j * 16 + lg * 4 + r;
        float gl = Ajl[j] * ck[r] + Bjl[j] * sk[r];
        float gh = Ajh[j] * ck[r] + Bjh[j] * sk[r];
        float xl = sl[j][r] * gl;
        float xh = sh[j][r] * gh;
        vl[j][r] = (kk > q_lo) ? -1e30f : xl;
        vh[j][r] = (kk > q_hi) ? -1e30f : xh;
      }
    // ---- row max ----
    float tml = vl[0][0], tmh = vh[0][0];
    #pragma unroll
    for (int j = 0; j < 4; ++j)
      #pragma unroll
      for (int r = 0; r < 4; ++r) { tml = fmaxf(tml, vl[j][r]); tmh = fmaxf(tmh, vh[j][r]); }
    tml = fmaxf(tml, __shfl_xor(tml, 16));
    tml = fmaxf(tml, __shfl_xor(tml, 32));
    tmh = fmaxf(tmh, __shfl_xor(tmh, 16));
    tmh = fmaxf(tmh, __shfl_xor(tmh, 32));
    // ---- defer-max rescale (rare; combined condition) ----
    if (__ballot(tml > m_lo + 8.0f || tmh > m_hi + 8.0f)) {
      float mnl = fmaxf(m_lo, tml), mnh = fmaxf(m_hi, tmh);
      float el = __expf(m_lo - mnl), eh = __expf(m_hi - mnh);
      m_lo = mnl; m_hi = mnh;
      l_lo *= el; l_hi *= eh;
      #pragma unroll
      for (int r = 0; r < 4; ++r) {
        float erl = __shfl(el, lg * 4 + r);
        float erh = __shfl(eh, lg * 4 + r);
        #pragma unroll
        for (int n = 0; n < 4; ++n) { o_lo[n][r] *= erl; o_hi[n][r] *= erh; }
      }
    }
    // ---- exp + row sum ----
    float el[4][4], eh[4][4], psl = 0.0f, psh = 0.0f;
    #pragma unroll
    for (int j = 0; j < 4; ++j)
      #pragma unroll
      for (int r = 0; r < 4; ++r) {
        el[j][r] = __expf(vl[j][r] - m_lo);
        eh[j][r] = __expf(vh[j][r] - m_hi);
        psl += el[j][r];
        psh += eh[j][r];
      }
    psl += __shfl_xor(psl, 16);
    psl += __shfl_xor(psl, 32);
    psh += __shfl_xor(psh, 16);
    psh += __shfl_xor(psh, 32);
    l_lo += psl; l_hi += psh;
    // ---- pack P via v_cvt_pk_bf16_f32 ----
    bf16x8 pal[2], pah[2];
    #pragma unroll
    for (int hh = 0; hh < 2; ++hh) {
      union { bf16x8 v8; unsigned u[4]; } ul, uh;
      ul.u[0] = pk_bf16(el[2 * hh][0], el[2 * hh][1]);
      ul.u[1] = pk_bf16(el[2 * hh][2], el[2 * hh][3]);
      ul.u[2] = pk_bf16(el[2 * hh + 1][0], el[2 * hh + 1][1]);
      ul.u[3] = pk_bf16(el[2 * hh + 1][2], el[2 * hh + 1][3]);
      uh.u[0] = pk_bf16(eh[2 * hh][0], eh[2 * hh][1]);
      uh.u[1] = pk_bf16(eh[2 * hh][2], eh[2 * hh][3]);
      uh.u[2] = pk_bf16(eh[2 * hh + 1][0], eh[2 * hh + 1][1]);
      uh.u[3] = pk_bf16(eh[2 * hh + 1][2], eh[2 * hh + 1][3]);
      pal[hh] = ul.v8; pah[hh] = uh.v8;
    }
    // ---- PV from LDS (V frags shared by lo/hi) ----
    #pragma unroll
    for (int n = 0; n < 4; ++n) {
      const int dbase = (n * 16 + lr) * 64;
      #pragma unroll
      for (int hh = 0; hh < 2; ++hh) {
        const int b0 = (hh * 64 + lg * 8) ^ kx;
        const int b1 = (hh * 64 + 32 + lg * 8) ^ kx;
        union { bf16x8 v8; uint2 u[2]; } uu;
        uu.u[0] = *(const uint2*)&Vsh[cur][dbase + (b0 >> 1)];
        uu.u[1] = *(const uint2*)&Vsh[cur][dbase + (b1 >> 1)];
        o_lo[n] = mfma16(pal[hh], uu.v8, o_lo[n]);
        o_hi[n] = mfma16(pah[hh], uu.v8, o_hi[n]);
      }
    }
    // ---- advance key trig ----
    #pragma unroll
    for (int r = 0; r < 4; ++r) {
      float t0 = ck[r] * cd8 - sk[r] * sd8;
      sk[r] = sk[r] * cd8 + ck[r] * sd8;
      ck[r] = t0;
    }
    __syncthreads();
    if (more) {
      const int nb = cur ^ 1;
      #pragma unroll
      for (int c = 0; c < 4; ++c) {
        int byte = (kce * 2 + c * 16) ^ ((kr & 7) << 4);
        *(uint4*)&Ksh[nb][kr * 128 + (byte >> 1)] = kreg[c];
      }
      #pragma unroll
      for (int c = 0; c < 2; ++c) {
        int byte = (vce * 2 + c * 16) ^ ((vd & 7) << 4);
        *(uint4*)&Vsh[nb][vd * 64 + (byte >> 1)] = vreg[c];
      }
      __syncthreads();
    }
  }
  // ---- epilogue ----
  #pragma unroll
  for (int r = 0; r < 4; ++r) {
    float lql = __shfl(l_lo, lg * 4 + r);
    float lqh = __shfl(l_hi, lg * 4 + r);
    const float invl = 1.0f / lql;
    const float invh = 1.0f / lqh;
    const int q = q_base + lg * 4 + r;
    ushort_t* OrowL = O + ((size_t)b * T_ + q) * C_ + h * 64;
    ushort_t* OrowH = O + ((size_t)b * T_ + q + 16) * C_ + h * 64;
    #pragma unroll
    for (int n = 0; n < 4; ++n) {
      OrowL[n * 16 + lr] = f2bf(o_lo[n][r] * invl);
      OrowH[n * 16 + lr] = f2bf(o_hi[n][r] * invh);
    }
  }
}

} // namespace

extern "C" void kernel_launch(void* const* d_in, const int* in_sizes, int n_in,
                              void* d_out, int out_size, void* d_ws, size_t ws_size,
                              hipStream_t stream) {
  const float* x  = (const float*)d_in[0];
  const float* Wq = (const float*)d_in[1];
  const float* Wk = (const float*)d_in[2];
  const float* Wv = (const float*)d_in[3];
  const float* Wo = (const float*)d_in[4];
  const float* th = (const float*)d_in[5];
  float* out = (float*)d_out;
  float* ws = (float*)d_ws;

  // ---- workspace layout (float offsets; total 22,020,096 floats = 88 MB) ----
  float* raw = ws;
  float* Vf  = raw;
  ushort_t* Ob  = (ushort_t*)(ws + 4194304);
  ushort_t* vt  = (ushort_t*)(ws + 6291456);
  ushort_t* Qb  = (ushort_t*)(ws + 8388608);
  ushort_t* Kb  = (ushort_t*)(ws + 12582912);
  ushort_t* xb  = (ushort_t*)(ws + 16777216);
  ushort_t* Wqt = (ushort_t*)(ws + 18874368);
  ushort_t* Wkt = (ushort_t*)(ws + 19922944);
  ushort_t* Wvt = (ushort_t*)(ws + 20971520);
  ushort_t* Wot = (ushort_t*)(ws + 21495808);

  dim3 blk(256);
  f32_to_bf16<<<4096, blk, 0, stream>>>(x, xb);
  wt_bf16<<<dim3(64, 32), blk, 0, stream>>>(Wq, Wqt, 1024, 2048);
  wt_bf16<<<dim3(64, 32), blk, 0, stream>>>(Wk, Wkt, 1024, 2048);
  wt_bf16<<<dim3(32, 32), blk, 0, stream>>>(Wv, Wvt, 1024, 1024);
  wt_bf16<<<dim3(32, 32), blk, 0, stream>>>(Wo, Wot, 1024, 1024);

  gemm_bt<<<dim3(16, 32), blk, 0, stream>>>(xb, Wqt, raw, 2048, 1024);
  qk_transform<<<16384, blk, 0, stream>>>(raw, Qb);
  gemm_bt<<<dim3(16, 32), blk, 0, stream>>>(xb, Wkt, raw, 2048, 1024);
  qk_transform<<<16384, blk, 0, stream>>>(raw, Kb);
  gemm_bt<<<dim3(8, 32), blk, 0, stream>>>(xb, Wvt, Vf, 1024, 1024);
  v_transpose<<<dim3(64, 32), blk, 0, stream>>>(Vf, vt);
  attn_mfma<<<512, blk, 0, stream>>>(Qb, Kb, vt, th, Ob);
  gemm_bt<<<dim3(8, 32), blk, 0, stream>>>(Ob, Wot, out, 1024, 1024);
}